// Round 10
// baseline (171.090 us; speedup 1.0000x reference)
//
#include <hip/hip_runtime.h>
#include <hip/hip_bf16.h>
#include <math.h>

// Problem constants
#define BB 2
#define MM 9          // 1 query + 8 supports
#define MS 8
#define DD 256
#define HW 2304       // 48*48
#define NCLS 4
#define OUTR 224

typedef float floatx4 __attribute__((ext_vector_type(4)));
typedef __bf16 bf16x8 __attribute__((ext_vector_type(8)));
typedef unsigned short ushortx8 __attribute__((ext_vector_type(8)));

// order-preserving float <-> uint encode for atomicMax
__device__ __forceinline__ unsigned enc_f(float f) {
    unsigned u = __float_as_uint(f);
    return (u & 0x80000000u) ? ~u : (u | 0x80000000u);
}
__device__ __forceinline__ float dec_f(unsigned k) {
    unsigned u = (k & 0x80000000u) ? (k & 0x7FFFFFFFu) : ~k;
    return __uint_as_float(u);
}

// ---------------- Kernel 1 (v3): per-pixel L2 normalize, transpose, cast bf16 ------------------
__global__ __launch_bounds__(256) void knorm(const float* __restrict__ emb,
                                             __hip_bfloat16* __restrict__ outp,
                                             unsigned* __restrict__ enc_logits) {
    __shared__ float tile[256][33];   // [d][pix], +1 pad
    __shared__ float psum[8][32];
    __shared__ float sscale[32];
    const int bm   = blockIdx.y;
    const int pix0 = blockIdx.x * 32;
    const int tid  = threadIdx.x;

    // fused init of encoded logits (BB*NCLS*HW = 18432 entries; key 0 < any enc(finite))
    int flat = (blockIdx.y * gridDim.x + blockIdx.x) * 256 + tid;
    if (flat < BB * NCLS * HW) enc_logits[flat] = 0u;

    const float* src = emb + (size_t)bm * DD * HW + pix0;
    {
        const int dr = tid >> 3;          // 0..31
        const int p4 = (tid & 7) * 4;     // 0..28
#pragma unroll
        for (int r = 0; r < 8; ++r) {
            int d = r * 32 + dr;
            floatx4 v = *(const floatx4*)(src + (size_t)d * HW + p4);
            float* t = &tile[d][p4];
            t[0] = v[0]; t[1] = v[1]; t[2] = v[2]; t[3] = v[3];
        }
    }
    __syncthreads();
    {
        const int pc = tid & 31;
        const int dr = tid >> 5;          // 0..7
        float ss = 0.f;
#pragma unroll
        for (int s = 0; s < 32; ++s) {
            float v = tile[dr * 32 + s][pc];
            ss += v * v;
        }
        psum[dr][pc] = ss;
    }
    __syncthreads();
    if (tid < 32) {
        float t = 0.f;
#pragma unroll
        for (int c = 0; c < 8; ++c) t += psum[c][tid];
        sscale[tid] = 1.0f / fmaxf(sqrtf(t), 1e-12f);
    }
    __syncthreads();
    __hip_bfloat16* dst = outp + (size_t)bm * HW * DD + (size_t)pix0 * DD;
#pragma unroll
    for (int r = 0; r < 32; ++r) {
        float v = tile[tid][r] * sscale[r];
        dst[(size_t)r * DD + tid] = __float2bfloat16(v);
    }
}

// ---------------- Kernel 2: 256x128-tile bf16 MFMA GEMM + fused masked max + atomicMax ---------
__device__ __forceinline__ void gld16(const unsigned short* g, unsigned short* l) {
    __builtin_amdgcn_global_load_lds((__attribute__((address_space(1))) void*)g,
                                     (__attribute__((address_space(3))) void*)l, 16, 0, 0);
}

#define BK 64
#define REDSTRIDE 260
// LDS: staging As(256x64) + Bs(128x64) bf16 = 49152 B; epilogue red[32][260] f32 = 33280 B
// (union). 49152 -> 3 blocks/CU (24 waves). Stride 260: 260%32=4 -> epilogue 2-way banks (free).
// launch_bounds(512,2): VGPR budget 256 -> no r8-style accumulator spill.
#define SMEM_BYTES 49152

// grid: (144 = m*18 + kt, 9 = 256-row tile, 2 = b); block 512 (8 waves, 4 row x 2 col)
__global__ __launch_bounds__(512, 2) void kgemm(const unsigned short* __restrict__ normed,
                                                const float* __restrict__ pm,
                                                unsigned* __restrict__ enc_logits) {
    __shared__ __attribute__((aligned(16))) unsigned char smem[SMEM_BYTES];
    unsigned short* As = (unsigned short*)smem;          // [256][64] row-major, chunk-swizzled
    unsigned short* Bs = As + 256 * 64;                  // [128][64]
    float* red = (float*)smem;                           // union (staging dead in epilogue)

    const int ct = blockIdx.x;       // 0..143
    const int rt = blockIdx.y;       // 0..8
    const int b  = blockIdx.z;
    const int m  = ct / 18;          // support index 0..7
    const int kt = ct % 18;          // col tile within support

    const int tid  = threadIdx.x;
    const int lane = tid & 63;
    const int wave = tid >> 6;       // 0..7
    const int wr = wave >> 1;        // 0..3 : 64-row quadrant
    const int wc = wave & 1;         // 0..1 : 64-col half
    const int lrow = lane & 15;
    const int quad = lane >> 4;      // 0..3

    const unsigned short* A  = normed + (size_t)(b * MM) * (HW * DD) + (size_t)(rt * 256) * DD;
    const unsigned short* Bp = normed + (size_t)(b * MM + 1 + m) * (HW * DD) + (size_t)(kt * 128) * DD;

    // ---- fused mask bits (per lane's 4 support columns) ----
    const float* pmB = pm + (size_t)(b * MS + m) * NCLS * HW;
    int mj[4];
#pragma unroll
    for (int j = 0; j < 4; ++j) {
        int kp = kt * 128 + wc * 64 + j * 16 + lrow;
        float p1 = pmB[HW + kp], p2 = pmB[2 * HW + kp], p3 = pmB[3 * HW + kp];
        mj[j] = ((p1 + p2 + p3 == 0.0f) ? 1 : 0) | (p1 != 0.0f ? 2 : 0) |
                (p2 != 0.0f ? 4 : 0) | (p3 != 0.0f ? 8 : 0);
    }

    // staging: lane l covers row r0+(l>>3); phys chunk p=l&7 holds logical chunk p^(row&7)
    const int srq  = lane >> 3;                  // row within 8-row group
    const int scol = ((lane & 7) ^ srq) * 8;     // logical chunk * 8 elems

    floatx4 zero = {0.f, 0.f, 0.f, 0.f};
    floatx4 acc[4][4];
#pragma unroll
    for (int i = 0; i < 4; ++i)
#pragma unroll
        for (int j = 0; j < 4; ++j) acc[i][j] = zero;

    for (int k0 = 0; k0 < DD; k0 += BK) {
        // A: wave stages rows [wave*32, wave*32+32) ; B: rows [wave*16, wave*16+16)
#pragma unroll
        for (int q = 0; q < 4; ++q) {
            int row = wave * 32 + q * 8 + srq;
            gld16(A + (size_t)row * DD + k0 + scol, As + (wave * 4 + q) * 512);
        }
#pragma unroll
        for (int q = 0; q < 2; ++q) {
            int row = wave * 16 + q * 8 + srq;
            gld16(Bp + (size_t)row * DD + k0 + scol, Bs + (wave * 2 + q) * 512);
        }
        __syncthreads();
#pragma unroll
        for (int kk = 0; kk < 2; ++kk) {
            bf16x8 af[4], bfr[4];
#pragma unroll
            for (int i = 0; i < 4; ++i) {
                int ar = wr * 64 + i * 16 + lrow;
                int br = wc * 64 + i * 16 + lrow;
                int pcA = (kk * 4 + quad) ^ (ar & 7);   // phys chunk (swizzled)
                int pcB = (kk * 4 + quad) ^ (br & 7);
                af[i]  = __builtin_bit_cast(bf16x8, *(const ushortx8*)(As + ar * 64 + pcA * 8));
                bfr[i] = __builtin_bit_cast(bf16x8, *(const ushortx8*)(Bs + br * 64 + pcB * 8));
            }
#pragma unroll
            for (int i = 0; i < 4; ++i)
#pragma unroll
                for (int j = 0; j < 4; ++j)
                    acc[i][j] = __builtin_amdgcn_mfma_f32_16x16x32_bf16(af[i], bfr[j], acc[i][j], 0, 0, 0);
        }
        __syncthreads();
    }

    // ---- epilogue: 4 per-class passes; masked j-reduce -> red[col32][row] -> 32-col max ----
    // lane's cols: wc*64 + j*16 + lrow ; rows: wr*64 + i*16 + quad*4 + r  (0..255)
    const int col32 = wc * 16 + lrow;

#pragma unroll
    for (int n = 0; n < NCLS; ++n) {
        if (n) __syncthreads();
        bool bit[4];
#pragma unroll
        for (int j = 0; j < 4; ++j) bit[j] = (mj[j] >> n) & 1;
#pragma unroll
        for (int i = 0; i < 4; ++i) {
            floatx4 o;
#pragma unroll
            for (int r = 0; r < 4; ++r) {
                float t0 = bit[0] ? acc[i][0][r] : -INFINITY;
                float t1 = bit[1] ? acc[i][1][r] : -INFINITY;
                float t2 = bit[2] ? acc[i][2][r] : -INFINITY;
                float t3 = bit[3] ? acc[i][3][r] : -INFINITY;
                o[r] = fmaxf(fmaxf(t0, t1), fmaxf(t2, t3));
            }
            int rowbase = wr * 64 + i * 16 + quad * 4;
            *(floatx4*)(red + (size_t)col32 * REDSTRIDE + rowbase) = o;
        }
        __syncthreads();
        if (tid < 256) {
            int row = tid;
            float v = -INFINITY;
#pragma unroll
            for (int c = 0; c < 32; ++c)
                v = fmaxf(v, red[(size_t)c * REDSTRIDE + row]);
            atomicMax(enc_logits + ((size_t)b * NCLS + n) * HW + rt * 256 + row, enc_f(v));
        }
    }
}

// ---------------- Kernel 3: bilinear 48 -> 224 (decode) + -inf fix on ch 0 ---------------------
__global__ __launch_bounds__(256) void kresize(const unsigned* __restrict__ enc_logits,
                                               float* __restrict__ out) {
    int idx = blockIdx.x * 256 + threadIdx.x;   // BB*NCLS*224*224
    if (idx >= BB * NCLS * OUTR * OUTR) return;
    int ox = idx % OUTR;
    int oy = (idx / OUTR) % OUTR;
    int bn = idx / (OUTR * OUTR);
    const unsigned* src = enc_logits + (size_t)bn * HW;
    const float inv = 48.0f / 224.0f;
    float sx = (ox + 0.5f) * inv - 0.5f;
    float sy = (oy + 0.5f) * inv - 0.5f;
    int x0 = (int)floorf(sx); float fx = sx - x0;
    int y0 = (int)floorf(sy); float fy = sy - y0;
    int x0c = min(max(x0, 0), 47), x1c = min(max(x0 + 1, 0), 47);
    int y0c = min(max(y0, 0), 47), y1c = min(max(y0 + 1, 0), 47);
    float v00 = dec_f(src[y0c * 48 + x0c]), v01 = dec_f(src[y0c * 48 + x1c]);
    float v10 = dec_f(src[y1c * 48 + x0c]), v11 = dec_f(src[y1c * 48 + x1c]);
    float v = (1.f - fy) * ((1.f - fx) * v00 + fx * v01) + fy * ((1.f - fx) * v10 + fx * v11);
    if ((bn & 3) == 0 && v == -INFINITY) v = 0.f;
    out[idx] = v;
}

// ---------------- launch ------------------------------------------------------------------------
extern "C" void kernel_launch(void* const* d_in, const int* in_sizes, int n_in,
                              void* d_out, int out_size, void* d_ws, size_t ws_size,
                              hipStream_t stream) {
    const float* emb = (const float*)d_in[0];   // (2,9,256,48,48) fp32
    const float* pm  = (const float*)d_in[1];   // (2,8,4,48,48) fp32
    float* out = (float*)d_out;                 // (2,4,224,224) fp32

    char* ws = (char*)d_ws;
    const size_t normed_bytes = (size_t)BB * MM * HW * DD * 2;   // 21,233,664
    __hip_bfloat16* normed = (__hip_bfloat16*)(ws);
    unsigned*       enc    = (unsigned*)(ws + normed_bytes);     // BB*NCLS*HW uints

    knorm<<<dim3(HW / 32, BB * MM), 256, 0, stream>>>(emb, normed, enc);
    kgemm<<<dim3(144, 9, BB), 512, 0, stream>>>((const unsigned short*)normed, pm, enc);
    kresize<<<(BB * NCLS * OUTR * OUTR + 255) / 256, 256, 0, stream>>>(enc, out);
}

// Round 11
// 144.115 us; speedup vs baseline: 1.1872x; 1.1872x over previous
//
#include <hip/hip_runtime.h>
#include <hip/hip_bf16.h>
#include <math.h>

// Problem constants
#define BB 2
#define MM 9          // 1 query + 8 supports
#define MS 8
#define DD 256
#define HW 2304       // 48*48
#define NCLS 4
#define OUTR 224

typedef float floatx4 __attribute__((ext_vector_type(4)));
typedef __bf16 bf16x8 __attribute__((ext_vector_type(8)));
typedef unsigned short ushortx8 __attribute__((ext_vector_type(8)));

// order-preserving float <-> uint encode for atomicMax
__device__ __forceinline__ unsigned enc_f(float f) {
    unsigned u = __float_as_uint(f);
    return (u & 0x80000000u) ? ~u : (u | 0x80000000u);
}
__device__ __forceinline__ float dec_f(unsigned k) {
    unsigned u = (k & 0x80000000u) ? (k & 0x7FFFFFFFu) : ~k;
    return __uint_as_float(u);
}

// ---------------- Kernel 1: per-pixel L2 normalize over D, transpose to [pix][d], cast bf16 ----
// r7-proven config: 32-pix tiles (33 KB LDS, 4 blocks/CU), float4 loads, dense bf16 stores.
__global__ __launch_bounds__(256) void knorm(const float* __restrict__ emb,
                                             __hip_bfloat16* __restrict__ outp,
                                             unsigned* __restrict__ enc_logits) {
    __shared__ float tile[256][33];   // [d][pix], +1 pad
    __shared__ float psum[8][32];
    __shared__ float sscale[32];
    const int bm   = blockIdx.y;
    const int pix0 = blockIdx.x * 32;
    const int tid  = threadIdx.x;

    // fused init of encoded logits (BB*NCLS*HW = 18432 entries; key 0 < any enc(finite))
    int flat = (blockIdx.y * gridDim.x + blockIdx.x) * 256 + tid;
    if (flat < BB * NCLS * HW) enc_logits[flat] = 0u;

    // ---- load: 8 iterations of float4; per iter wave covers 8 d-rows x 128B ----
    const float* src = emb + (size_t)bm * DD * HW + pix0;
    {
        const int dr = tid >> 3;          // 0..31
        const int p4 = (tid & 7) * 4;     // 0..28
#pragma unroll
        for (int r = 0; r < 8; ++r) {
            int d = r * 32 + dr;
            floatx4 v = *(const floatx4*)(src + (size_t)d * HW + p4);
            float* t = &tile[d][p4];
            t[0] = v[0]; t[1] = v[1]; t[2] = v[2]; t[3] = v[3];
        }
    }
    __syncthreads();
    // ---- sum of squares: thread (chunk=dr, pix=pc) sums 32 d's ----
    {
        const int pc = tid & 31;
        const int dr = tid >> 5;          // 0..7
        float ss = 0.f;
#pragma unroll
        for (int s = 0; s < 32; ++s) {
            float v = tile[dr * 32 + s][pc];
            ss += v * v;
        }
        psum[dr][pc] = ss;
    }
    __syncthreads();
    if (tid < 32) {
        float t = 0.f;
#pragma unroll
        for (int c = 0; c < 8; ++c) t += psum[c][tid];
        sscale[tid] = 1.0f / fmaxf(sqrtf(t), 1e-12f);
    }
    __syncthreads();
    // ---- store: thread=d, r=pixel; 512B dense per r across the block ----
    __hip_bfloat16* dst = outp + (size_t)bm * HW * DD + (size_t)pix0 * DD;
#pragma unroll
    for (int r = 0; r < 32; ++r) {
        float v = tile[tid][r] * sscale[r];
        dst[(size_t)r * DD + tid] = __float2bfloat16(v);
    }
}

// ---------------- Kernel 2: bf16 MFMA GEMM + fused mask + per-class masked max + atomicMax -----
// Measured local optimum (r7): 128x128 tile, BK=64, 4 waves, XOR-swizzled staging
// (zero bank conflicts), LDS-transpose epilogue, order-preserving atomicMax output.
// Neighborhood explored and rejected: (256,5) -> VGPR spill (r8); 32 KB LDS / 5 blocks/CU
// -> +atomic/L2 pressure (r9); 256x128 tile -> barrier convoy (r10); fused resize tail
// -> device-fence catastrophe (r6).
__device__ __forceinline__ void gld16(const unsigned short* g, unsigned short* l) {
    __builtin_amdgcn_global_load_lds((__attribute__((address_space(1))) void*)g,
                                     (__attribute__((address_space(3))) void*)l, 16, 0, 0);
}

#define BK 64
#define REDSTRIDE 132
// LDS: staging As+Bs = 32768 B; epilogue red[2][32][132] f32 = 33792 B (union)
#define SMEM_BYTES 33792

// grid: (144 = m*18 + kt, 18 = row tile, 2 = b); block 256 (4 waves)
__global__ __launch_bounds__(256, 4) void kgemm(const unsigned short* __restrict__ normed,
                                                const float* __restrict__ pm,
                                                unsigned* __restrict__ enc_logits) {
    __shared__ __attribute__((aligned(16))) unsigned char smem[SMEM_BYTES];
    unsigned short* As = (unsigned short*)smem;          // [128][64] row-major, chunk-swizzled
    unsigned short* Bs = As + 128 * 64;
    float* red = (float*)smem;                           // union (staging dead in epilogue)

    const int ct = blockIdx.x;       // 0..143
    const int rt = blockIdx.y;       // 0..17
    const int b  = blockIdx.z;
    const int m  = ct / 18;          // support index 0..7
    const int kt = ct % 18;          // col tile within support

    const int tid  = threadIdx.x;
    const int lane = tid & 63;
    const int wave = tid >> 6;
    const int wr = wave >> 1, wc = wave & 1;
    const int lrow = lane & 15;
    const int quad = lane >> 4;      // 0..3

    const unsigned short* A  = normed + (size_t)(b * MM) * (HW * DD) + (size_t)(rt * 128) * DD;
    const unsigned short* Bp = normed + (size_t)(b * MM + 1 + m) * (HW * DD) + (size_t)(kt * 128) * DD;

    // ---- fused mask bits ----
    const float* pmB = pm + (size_t)(b * MS + m) * NCLS * HW;
    int mj[4];
#pragma unroll
    for (int j = 0; j < 4; ++j) {
        int kp = kt * 128 + wc * 64 + j * 16 + lrow;
        float p1 = pmB[HW + kp], p2 = pmB[2 * HW + kp], p3 = pmB[3 * HW + kp];
        mj[j] = ((p1 + p2 + p3 == 0.0f) ? 1 : 0) | (p1 != 0.0f ? 2 : 0) |
                (p2 != 0.0f ? 4 : 0) | (p3 != 0.0f ? 8 : 0);
    }

    // staging: lane l covers row r0+(l>>3), phys chunk p=l&7 holds logical chunk p^(row&7).
    const int srq  = lane >> 3;                  // row within 8-row group
    const int scol = ((lane & 7) ^ srq) * 8;     // logical chunk * 8 elems

    floatx4 zero = {0.f, 0.f, 0.f, 0.f};
    floatx4 acc[4][4];
#pragma unroll
    for (int i = 0; i < 4; ++i)
#pragma unroll
        for (int j = 0; j < 4; ++j) acc[i][j] = zero;

    for (int k0 = 0; k0 < DD; k0 += BK) {
#pragma unroll
        for (int q = 0; q < 4; ++q) {
            int row = wave * 32 + q * 8 + srq;
            gld16(A  + (size_t)row * DD + k0 + scol, As + (wave * 4 + q) * 512);
            gld16(Bp + (size_t)row * DD + k0 + scol, Bs + (wave * 4 + q) * 512);
        }
        __syncthreads();
#pragma unroll
        for (int kk = 0; kk < 2; ++kk) {
            bf16x8 af[4], bfr[4];
#pragma unroll
            for (int i = 0; i < 4; ++i) {
                int ar = wr * 64 + i * 16 + lrow;
                int br = wc * 64 + i * 16 + lrow;
                int pcA = (kk * 4 + quad) ^ (ar & 7);   // phys chunk (swizzled)
                int pcB = (kk * 4 + quad) ^ (br & 7);
                af[i]  = __builtin_bit_cast(bf16x8, *(const ushortx8*)(As + ar * 64 + pcA * 8));
                bfr[i] = __builtin_bit_cast(bf16x8, *(const ushortx8*)(Bs + br * 64 + pcB * 8));
            }
#pragma unroll
            for (int i = 0; i < 4; ++i)
#pragma unroll
                for (int j = 0; j < 4; ++j)
                    acc[i][j] = __builtin_amdgcn_mfma_f32_16x16x32_bf16(af[i], bfr[j], acc[i][j], 0, 0, 0);
        }
        __syncthreads();
    }

    // ---- epilogue: per-class masked max, LDS transpose-reduce, atomicMax ----
    const int col32 = wc * 16 + lrow;

#pragma unroll
    for (int p = 0; p < 2; ++p) {
        if (p) __syncthreads();
        bool bit[2][4];
#pragma unroll
        for (int nn = 0; nn < 2; ++nn) {
            int n = p * 2 + nn;
#pragma unroll
            for (int j = 0; j < 4; ++j) bit[nn][j] = (mj[j] >> n) & 1;
        }
#pragma unroll
        for (int nn = 0; nn < 2; ++nn) {
#pragma unroll
            for (int i = 0; i < 4; ++i) {
                floatx4 o;
#pragma unroll
                for (int r = 0; r < 4; ++r) {
                    float t0 = bit[nn][0] ? acc[i][0][r] : -INFINITY;
                    float t1 = bit[nn][1] ? acc[i][1][r] : -INFINITY;
                    float t2 = bit[nn][2] ? acc[i][2][r] : -INFINITY;
                    float t3 = bit[nn][3] ? acc[i][3][r] : -INFINITY;
                    o[r] = fmaxf(fmaxf(t0, t1), fmaxf(t2, t3));
                }
                int rowbase = wr * 64 + i * 16 + quad * 4;
                *(floatx4*)(red + ((size_t)(nn * 32 + col32)) * REDSTRIDE + rowbase) = o;
            }
        }
        __syncthreads();
        {
            int nn  = tid >> 7;
            int row = tid & 127;
            float v = -INFINITY;
#pragma unroll
            for (int c = 0; c < 32; ++c)
                v = fmaxf(v, red[((size_t)(nn * 32 + c)) * REDSTRIDE + row]);
            int n = p * 2 + nn;
            atomicMax(enc_logits + ((size_t)b * NCLS + n) * HW + rt * 128 + row, enc_f(v));
        }
    }
}

// ---------------- Kernel 3: bilinear 48 -> 224 (decode) + -inf fix on ch 0 ---------------------
__global__ __launch_bounds__(256) void kresize(const unsigned* __restrict__ enc_logits,
                                               float* __restrict__ out) {
    int idx = blockIdx.x * 256 + threadIdx.x;   // BB*NCLS*224*224
    if (idx >= BB * NCLS * OUTR * OUTR) return;
    int ox = idx % OUTR;
    int oy = (idx / OUTR) % OUTR;
    int bn = idx / (OUTR * OUTR);
    const unsigned* src = enc_logits + (size_t)bn * HW;
    const float inv = 48.0f / 224.0f;
    float sx = (ox + 0.5f) * inv - 0.5f;
    float sy = (oy + 0.5f) * inv - 0.5f;
    int x0 = (int)floorf(sx); float fx = sx - x0;
    int y0 = (int)floorf(sy); float fy = sy - y0;
    int x0c = min(max(x0, 0), 47), x1c = min(max(x0 + 1, 0), 47);
    int y0c = min(max(y0, 0), 47), y1c = min(max(y0 + 1, 0), 47);
    float v00 = dec_f(src[y0c * 48 + x0c]), v01 = dec_f(src[y0c * 48 + x1c]);
    float v10 = dec_f(src[y1c * 48 + x0c]), v11 = dec_f(src[y1c * 48 + x1c]);
    float v = (1.f - fy) * ((1.f - fx) * v00 + fx * v01) + fy * ((1.f - fx) * v10 + fx * v11);
    if ((bn & 3) == 0 && v == -INFINITY) v = 0.f;
    out[idx] = v;
}

// ---------------- launch ------------------------------------------------------------------------
extern "C" void kernel_launch(void* const* d_in, const int* in_sizes, int n_in,
                              void* d_out, int out_size, void* d_ws, size_t ws_size,
                              hipStream_t stream) {
    const float* emb = (const float*)d_in[0];   // (2,9,256,48,48) fp32
    const float* pm  = (const float*)d_in[1];   // (2,8,4,48,48) fp32
    float* out = (float*)d_out;                 // (2,4,224,224) fp32

    char* ws = (char*)d_ws;
    const size_t normed_bytes = (size_t)BB * MM * HW * DD * 2;   // 21,233,664
    __hip_bfloat16* normed = (__hip_bfloat16*)(ws);
    unsigned*       enc    = (unsigned*)(ws + normed_bytes);     // BB*NCLS*HW uints

    knorm<<<dim3(HW / 32, BB * MM), 256, 0, stream>>>(emb, normed, enc);
    kgemm<<<dim3(144, 18, BB), 256, 0, stream>>>((const unsigned short*)normed, pm, enc);
    kresize<<<(BB * NCLS * OUTR * OUTR + 255) / 256, 256, 0, stream>>>(enc, out);
}